// Round 1
// baseline (135.659 us; speedup 1.0000x reference)
//
#include <hip/hip_runtime.h>
#include <math.h>

// SoftAvULoss: N x C (524288 x 100) f32 logits, int labels -> scalar loss.
// Lane-per-row design: each 64-thread block (1 wave) stages a 64x100 tile
// into LDS (coalesced float4), then each lane processes its own row.
// LDS row stride 102 dwords: 8B-aligned for b64 ops, 2-way bank alias (free).

#define C_COLS 100
#define ROWS_PER_TILE 64
#define LDS_STRIDE 102  // dwords per row in LDS

__global__ __launch_bounds__(64) void avu_main(const float* __restrict__ logits,
                                               const int* __restrict__ labels,
                                               float* __restrict__ ws,
                                               int ntiles) {
    __shared__ float lds[ROWS_PER_TILE * LDS_STRIDE];
    const int lane = threadIdx.x;  // 0..63

    float s_ac = 0.f, s_au = 0.f, s_ic = 0.f, s_iu = 0.f;

    for (int tile = blockIdx.x; tile < ntiles; tile += gridDim.x) {
        const size_t tile_dw = (size_t)tile * (ROWS_PER_TILE * C_COLS);
        const float4* gsrc = (const float4*)(logits + tile_dw);

        // ---- stage tile: 1600 float4 (6400 dwords), fully contiguous in global.
        // float4 #f covers dwords 4f..4f+3; since C%4==0 it never crosses a row.
        #pragma unroll
        for (int k = 0; k < 25; ++k) {
            const int f = lane + (k << 6);       // 0..1599
            const float4 v = gsrc[f];
            const int row = f / 25;              // 25 float4 per row
            const int c4  = (f - row * 25) * 4;  // dword col 0,4,...,96
            float* dst = &lds[row * LDS_STRIDE + c4];
            ((float2*)dst)[0] = make_float2(v.x, v.y);
            ((float2*)dst)[1] = make_float2(v.z, v.w);
        }
        __syncthreads();

        // ---- pass 1: max + first-occurrence argmax over this lane's row
        const float2* rowp = (const float2*)&lds[lane * LDS_STRIDE];
        float m = -INFINITY;
        int idx = 0;
        #pragma unroll
        for (int c = 0; c < 50; ++c) {
            const float2 v = rowp[c];
            if (v.x > m) { m = v.x; idx = 2 * c; }
            if (v.y > m) { m = v.y; idx = 2 * c + 1; }
        }

        // ---- pass 2: S = sum exp(x-m), W = sum exp(x-m)*(x-m)
        float S = 0.f, W = 0.f;
        #pragma unroll
        for (int c = 0; c < 50; ++c) {
            const float2 v = rowp[c];
            const float d0 = v.x - m, d1 = v.y - m;
            const float e0 = __expf(d0), e1 = __expf(d1);
            S += e0 + e1;
            W += e0 * d0 + e1 * d1;
        }
        const float H = __logf(S) - W / S;   // entropy (== -sum p log p)

        // ---- per-row scalars
        const float en = H * (1.0f / C_COLS);           // normalized entropy
        // K=0.5 -> z = (1/TEMP) * (log(en) - log(1-en)), TEMP=0.01
        const float z = 100.0f * (__logf(en) - __logf(1.0f - en));
        const float su = (z >= 0.f) ? 1.0f / (1.0f + __expf(-z))
                                    : __expf(z) / (1.0f + __expf(z));
        const float e2  = __expf(2.0f * H);
        const float t   = (e2 - 1.0f) / (e2 + 1.0f);    // tanh(H)
        const float omt = 2.0f / (e2 + 1.0f);           // 1 - tanh(H), stable

        const float cterm = (1.0f - su) * omt;
        const float uterm = su * t;

        const int lab = labels[tile * ROWS_PER_TILE + lane];
        if (lab == idx) { s_ac += cterm; s_au += uterm; }
        else            { s_ic += cterm; s_iu += uterm; }

        __syncthreads();  // protect LDS from next tile's writes (WAR)
    }

    // ---- wave reduction of the 4 partials
    #pragma unroll
    for (int off = 32; off > 0; off >>= 1) {
        s_ac += __shfl_xor(s_ac, off);
        s_au += __shfl_xor(s_au, off);
        s_ic += __shfl_xor(s_ic, off);
        s_iu += __shfl_xor(s_iu, off);
    }
    if (lane == 0) {
        atomicAdd(&ws[0], s_ac);
        atomicAdd(&ws[1], s_au);
        atomicAdd(&ws[2], s_ic);
        atomicAdd(&ws[3], s_iu);
    }
}

__global__ void avu_final(const float* __restrict__ ws, float* __restrict__ out) {
    const float ac = ws[0], au = ws[1], ic = ws[2], iu = ws[3];
    const float avu = (ac + iu) / (ac + au + ic + iu + 1e-10f);
    out[0] = -logf(avu + 1e-10f);
}

extern "C" void kernel_launch(void* const* d_in, const int* in_sizes, int n_in,
                              void* d_out, int out_size, void* d_ws, size_t ws_size,
                              hipStream_t stream) {
    const float* logits = (const float*)d_in[0];
    const int*   labels = (const int*)d_in[1];
    float* out = (float*)d_out;
    float* ws  = (float*)d_ws;

    const int nrows  = in_sizes[1];          // 524288
    const int ntiles = nrows / ROWS_PER_TILE; // 8192 (exact)

    hipMemsetAsync(ws, 0, 4 * sizeof(float), stream);

    int grid = ntiles < 2048 ? ntiles : 2048;
    avu_main<<<grid, 64, 0, stream>>>(logits, labels, ws, ntiles);
    avu_final<<<1, 1, 0, stream>>>(ws, out);
}

// Round 2
// 133.851 us; speedup vs baseline: 1.0135x; 1.0135x over previous
//
#include <hip/hip_runtime.h>
#include <math.h>

// SoftAvULoss: N x C (524288 x 100) f32 logits, int labels -> scalar loss.
// One thread per row; online softmax in registers (running m, S, W).
// accurate <=> logits[row][label] == rowmax  (exact; ties measure-zero).
// No LDS staging -> occupancy limited only by VGPRs (~60), not 26KB LDS.

#define C_COLS 100

__global__ __launch_bounds__(256) void avu_main(const float* __restrict__ logits,
                                                const int* __restrict__ labels,
                                                float* __restrict__ ws,
                                                int nrows) {
    const int row = blockIdx.x * 256 + threadIdx.x;

    float cterm = 0.f, uterm = 0.f;
    bool acc = false;

    if (row < nrows) {
        const int lab = labels[row];                          // coalesced 4B
        const float xl = logits[(size_t)row * C_COLS + lab];  // line reused by stream below
        const float4* rp = (const float4*)(logits + (size_t)row * C_COLS);

        float m = -3.0e38f, S = 0.f, W = 0.f;
        #pragma unroll
        for (int k = 0; k < 25; ++k) {
            const float4 v = rp[k];
            // chunk max (no index tracking needed)
            const float cmax = fmaxf(fmaxf(v.x, v.y), fmaxf(v.z, v.w));
            const float mold = m;
            m = fmaxf(m, cmax);
            // rescale running sums to new max:
            // S' = e^{mold-m} S ;  W' = e^{mold-m} (W + (mold-m) S)
            const float t  = mold - m;     // <= 0, finite math (m0 = -3e38)
            const float sc = __expf(t);
            W = sc * (W + t * S);
            S = sc * S;
            // accumulate chunk
            const float d0 = v.x - m, d1 = v.y - m, d2 = v.z - m, d3 = v.w - m;
            const float e0 = __expf(d0), e1 = __expf(d1);
            const float e2 = __expf(d2), e3 = __expf(d3);
            S += (e0 + e1) + (e2 + e3);
            W += (e0 * d0 + e1 * d1) + (e2 * d2 + e3 * d3);
        }

        const float H  = __logf(S) - W / S;          // entropy = -sum p log p
        const float en = H * (1.0f / C_COLS);
        // K=0.5 -> z = (1/TEMP)*(log en - log(1-en)), TEMP=0.01
        const float z  = 100.0f * (__logf(en) - __logf(1.0f - en));
        const float su = (z >= 0.f) ? 1.0f / (1.0f + __expf(-z))
                                    : __expf(z) / (1.0f + __expf(z));
        const float e2h = __expf(2.0f * H);
        const float th  = (e2h - 1.0f) / (e2h + 1.0f);  // tanh(H)
        const float omt = 2.0f / (e2h + 1.0f);          // 1 - tanh(H), stable

        cterm = (1.0f - su) * omt;
        uterm = su * th;
        acc   = (xl == m);
    }

    float s_ac = acc ? cterm : 0.f;
    float s_au = acc ? uterm : 0.f;
    float s_ic = acc ? 0.f : cterm;
    float s_iu = acc ? 0.f : uterm;

    // wave reduction
    #pragma unroll
    for (int off = 32; off > 0; off >>= 1) {
        s_ac += __shfl_xor(s_ac, off);
        s_au += __shfl_xor(s_au, off);
        s_ic += __shfl_xor(s_ic, off);
        s_iu += __shfl_xor(s_iu, off);
    }

    // cross-wave reduction (4 waves/block), then 4 atomics per block
    __shared__ float red[4][4];
    const int wid = threadIdx.x >> 6;
    if ((threadIdx.x & 63) == 0) {
        red[wid][0] = s_ac; red[wid][1] = s_au;
        red[wid][2] = s_ic; red[wid][3] = s_iu;
    }
    __syncthreads();
    if (threadIdx.x == 0) {
        const float a = red[0][0] + red[1][0] + red[2][0] + red[3][0];
        const float b = red[0][1] + red[1][1] + red[2][1] + red[3][1];
        const float c = red[0][2] + red[1][2] + red[2][2] + red[3][2];
        const float d = red[0][3] + red[1][3] + red[2][3] + red[3][3];
        atomicAdd(&ws[0], a);
        atomicAdd(&ws[1], b);
        atomicAdd(&ws[2], c);
        atomicAdd(&ws[3], d);
    }
}

__global__ void avu_final(const float* __restrict__ ws, float* __restrict__ out) {
    const float ac = ws[0], au = ws[1], ic = ws[2], iu = ws[3];
    const float avu = (ac + iu) / (ac + au + ic + iu + 1e-10f);
    out[0] = -logf(avu + 1e-10f);
}

extern "C" void kernel_launch(void* const* d_in, const int* in_sizes, int n_in,
                              void* d_out, int out_size, void* d_ws, size_t ws_size,
                              hipStream_t stream) {
    const float* logits = (const float*)d_in[0];
    const int*   labels = (const int*)d_in[1];
    float* out = (float*)d_out;
    float* ws  = (float*)d_ws;

    const int nrows = in_sizes[1];               // 524288
    const int grid  = (nrows + 255) / 256;       // 2048

    hipMemsetAsync(ws, 0, 4 * sizeof(float), stream);
    avu_main<<<grid, 256, 0, stream>>>(logits, labels, ws, nrows);
    avu_final<<<1, 1, 0, stream>>>(ws, out);
}

// Round 3
// 130.919 us; speedup vs baseline: 1.0362x; 1.0224x over previous
//
#include <hip/hip_runtime.h>
#include <math.h>

// SoftAvULoss: N x C (524288 x 100) f32 logits, int32 labels -> scalar loss.
// 4 lanes per row, 16 rows per wave. Each lane holds its 25-element row
// quarter in registers (6 float4 + 1 scalar, ALL issued before use -> deep
// MLP), computes local (max, S=sum e^{x-m}, W=sum e^{x-m}(x-m)), then a
// 2-step shfl_xor flash-merge produces the row softmax stats.
// accurate <=> logits[row][label] == rowmax (exact, ties measure-zero).

#define C_COLS 100

__global__ __launch_bounds__(256) void avu_main(const float* __restrict__ logits,
                                                const int* __restrict__ labels,
                                                float* __restrict__ ws,
                                                int ntiles) {
    const int tid  = threadIdx.x;
    const int lane = tid & 63;
    const int wid  = tid >> 6;       // wave in block (0..3)
    const int s    = lane & 3;       // sublane within row group
    const int rsub = lane >> 2;      // row within wave (0..15)

    float s_ac = 0.f, s_au = 0.f, s_ic = 0.f, s_iu = 0.f;

    for (int tile = blockIdx.x; tile < ntiles; tile += gridDim.x) {
        const int row = tile * 64 + wid * 16 + rsub;
        const float* base = logits + (size_t)row * C_COLS;

        // scattered per-row pair (only 16 lanes), needed only at the tail:
        int lab = 0; float xl = 0.f;
        if (s == 0) { lab = labels[row]; xl = base[lab]; }

        // ---- issue all row-quarter loads up front (independent, stay in flight)
        // lane covers cols {4s..4s+3} + 16k for k=0..5, plus col 96+s.
        const float* p = base + 4 * s;
        const float4 v0 = *(const float4*)(p +  0);
        const float4 v1 = *(const float4*)(p + 16);
        const float4 v2 = *(const float4*)(p + 32);
        const float4 v3 = *(const float4*)(p + 48);
        const float4 v4 = *(const float4*)(p + 64);
        const float4 v5 = *(const float4*)(p + 80);
        const float  tl = base[96 + s];

        // ---- local max over 25 elems
        float m = fmaxf(fmaxf(fmaxf(v0.x, v0.y), fmaxf(v0.z, v0.w)),
                  fmaxf(fmaxf(fmaxf(v1.x, v1.y), fmaxf(v1.z, v1.w)),
                  fmaxf(fmaxf(fmaxf(v2.x, v2.y), fmaxf(v2.z, v2.w)),
                  fmaxf(fmaxf(fmaxf(v3.x, v3.y), fmaxf(v3.z, v3.w)),
                  fmaxf(fmaxf(fmaxf(v4.x, v4.y), fmaxf(v4.z, v4.w)),
                  fmaxf(fmaxf(fmaxf(v5.x, v5.y), fmaxf(v5.z, v5.w)), tl))))));

        // ---- local S = sum e^{x-m}, W = sum e^{x-m}(x-m)
        float S = 0.f, W = 0.f;
        {
            const float4 vv[6] = {v0, v1, v2, v3, v4, v5};
            #pragma unroll
            for (int k = 0; k < 6; ++k) {
                const float d0 = vv[k].x - m, d1 = vv[k].y - m;
                const float d2 = vv[k].z - m, d3 = vv[k].w - m;
                const float e0 = __expf(d0), e1 = __expf(d1);
                const float e2 = __expf(d2), e3 = __expf(d3);
                S += (e0 + e1) + (e2 + e3);
                W += (e0 * d0 + e1 * d1) + (e2 * d2 + e3 * d3);
            }
            const float dt = tl - m;
            const float et = __expf(dt);
            S += et; W += et * dt;
        }

        // ---- merge (m,S,W) across the 4 sublanes (flash-attention style)
        #pragma unroll
        for (int d = 1; d <= 2; d <<= 1) {
            const float mo = __shfl_xor(m, d);
            const float So = __shfl_xor(S, d);
            const float Wo = __shfl_xor(W, d);
            const float mn = fmaxf(m, mo);
            const float da = m - mn, db = mo - mn;
            const float ea = __expf(da), eb = __expf(db);
            const float Wn = ea * (W + da * S) + eb * (Wo + db * So);
            S = ea * S + eb * So;
            W = Wn;
            m = mn;
        }

        // ---- per-row scalars (all 4 sublanes compute identically; s==0 accumulates)
        const float H  = __logf(S) - W / S;          // entropy
        const float en = H * (1.0f / C_COLS);
        const float z  = 100.0f * (__logf(en) - __logf(1.0f - en)); // K=0.5, TEMP=0.01
        const float su = (z >= 0.f) ? 1.0f / (1.0f + __expf(-z))
                                    : __expf(z) / (1.0f + __expf(z));
        const float e2h = __expf(2.0f * H);
        const float th  = (e2h - 1.0f) / (e2h + 1.0f);  // tanh(H)
        const float omt = 2.0f / (e2h + 1.0f);          // 1 - tanh(H), stable

        const float cterm = (1.0f - su) * omt;
        const float uterm = su * th;

        if (s == 0) {
            if (xl == m) { s_ac += cterm; s_au += uterm; }
            else         { s_ic += cterm; s_iu += uterm; }
        }
    }

    // ---- wave reduction of the 4 partials
    #pragma unroll
    for (int off = 32; off > 0; off >>= 1) {
        s_ac += __shfl_xor(s_ac, off);
        s_au += __shfl_xor(s_au, off);
        s_ic += __shfl_xor(s_ic, off);
        s_iu += __shfl_xor(s_iu, off);
    }

    // ---- cross-wave reduction (4 waves/block), 4 atomics per block
    __shared__ float red[4][4];
    if ((tid & 63) == 0) {
        red[wid][0] = s_ac; red[wid][1] = s_au;
        red[wid][2] = s_ic; red[wid][3] = s_iu;
    }
    __syncthreads();
    if (tid == 0) {
        const float a = red[0][0] + red[1][0] + red[2][0] + red[3][0];
        const float b = red[0][1] + red[1][1] + red[2][1] + red[3][1];
        const float c = red[0][2] + red[1][2] + red[2][2] + red[3][2];
        const float d = red[0][3] + red[1][3] + red[2][3] + red[3][3];
        atomicAdd(&ws[0], a);
        atomicAdd(&ws[1], b);
        atomicAdd(&ws[2], c);
        atomicAdd(&ws[3], d);
    }
}

__global__ void avu_final(const float* __restrict__ ws, float* __restrict__ out) {
    const float ac = ws[0], au = ws[1], ic = ws[2], iu = ws[3];
    const float avu = (ac + iu) / (ac + au + ic + iu + 1e-10f);
    out[0] = -logf(avu + 1e-10f);
}

extern "C" void kernel_launch(void* const* d_in, const int* in_sizes, int n_in,
                              void* d_out, int out_size, void* d_ws, size_t ws_size,
                              hipStream_t stream) {
    const float* logits = (const float*)d_in[0];
    const int*   labels = (const int*)d_in[1];
    float* out = (float*)d_out;
    float* ws  = (float*)d_ws;

    const int nrows  = in_sizes[1];          // 524288
    const int ntiles = nrows / 64;           // 8192 (exact)

    hipMemsetAsync(ws, 0, 4 * sizeof(float), stream);

    const int grid = ntiles < 2048 ? ntiles : 2048;
    avu_main<<<grid, 256, 0, stream>>>(logits, labels, ws, ntiles);
    avu_final<<<1, 1, 0, stream>>>(ws, out);
}

// Round 4
// 39.752 us; speedup vs baseline: 3.4127x; 3.2934x over previous
//
#include <hip/hip_runtime.h>
#include <math.h>

// SoftAvULoss: N x C (524288 x 100) f32 logits, int32 labels -> scalar loss.
// 4 lanes per row, 16 rows per wave; row quarter held in registers (6 float4
// + 1 scalar issued up front), local (m, S=sum e^{x-m}, W=sum e^{x-m}(x-m)),
// 2-step shfl_xor flash-merge -> row stats.
// accurate <=> logits[row][label] == rowmax (exact, ties measure-zero).
//
// R4 change: NO atomics. All three prior rounds were pinned at ~139us by a
// serialized chain of 8192 same-address atomicAdds (L3-warm replays with ~0
// HBM traffic ran at identical speed -> epilogue-bound, not data-path-bound).
// Each block now stores its 4 partials to a private float4 ws slot; a second
// 256-thread kernel reduces the 1024 slots and computes the loss.

#define C_COLS 100
#define GRID_MAIN 1024

__global__ __launch_bounds__(256) void avu_main(const float* __restrict__ logits,
                                                const int* __restrict__ labels,
                                                float4* __restrict__ partials,
                                                int ntiles) {
    const int tid  = threadIdx.x;
    const int lane = tid & 63;
    const int wid  = tid >> 6;       // wave in block (0..3)
    const int s    = lane & 3;       // sublane within row group
    const int rsub = lane >> 2;      // row within wave (0..15)

    float s_ac = 0.f, s_au = 0.f, s_ic = 0.f, s_iu = 0.f;

    for (int tile = blockIdx.x; tile < ntiles; tile += gridDim.x) {
        const int row = tile * 64 + wid * 16 + rsub;
        const float* base = logits + (size_t)row * C_COLS;

        // scattered per-row pair (16 active lanes), needed only at the tail:
        float xl = 0.f;
        if (s == 0) { xl = base[labels[row]]; }

        // ---- issue all row-quarter loads up front
        const float* p = base + 4 * s;
        const float4 v0 = *(const float4*)(p +  0);
        const float4 v1 = *(const float4*)(p + 16);
        const float4 v2 = *(const float4*)(p + 32);
        const float4 v3 = *(const float4*)(p + 48);
        const float4 v4 = *(const float4*)(p + 64);
        const float  tl = base[96 + s];
        const float4 v5 = *(const float4*)(p + 80);

        // ---- local max over 25 elems
        float m = fmaxf(fmaxf(fmaxf(v0.x, v0.y), fmaxf(v0.z, v0.w)),
                  fmaxf(fmaxf(fmaxf(v1.x, v1.y), fmaxf(v1.z, v1.w)),
                  fmaxf(fmaxf(fmaxf(v2.x, v2.y), fmaxf(v2.z, v2.w)),
                  fmaxf(fmaxf(fmaxf(v3.x, v3.y), fmaxf(v3.z, v3.w)),
                  fmaxf(fmaxf(fmaxf(v4.x, v4.y), fmaxf(v4.z, v4.w)),
                  fmaxf(fmaxf(fmaxf(v5.x, v5.y), fmaxf(v5.z, v5.w)), tl))))));

        // ---- local S, W
        float S = 0.f, W = 0.f;
        {
            const float4 vv[6] = {v0, v1, v2, v3, v4, v5};
            #pragma unroll
            for (int k = 0; k < 6; ++k) {
                const float d0 = vv[k].x - m, d1 = vv[k].y - m;
                const float d2 = vv[k].z - m, d3 = vv[k].w - m;
                const float e0 = __expf(d0), e1 = __expf(d1);
                const float e2 = __expf(d2), e3 = __expf(d3);
                S += (e0 + e1) + (e2 + e3);
                W += (e0 * d0 + e1 * d1) + (e2 * d2 + e3 * d3);
            }
            const float dt = tl - m;
            const float et = __expf(dt);
            S += et; W += et * dt;
        }

        // ---- merge (m,S,W) across the 4 sublanes
        #pragma unroll
        for (int d = 1; d <= 2; d <<= 1) {
            const float mo = __shfl_xor(m, d);
            const float So = __shfl_xor(S, d);
            const float Wo = __shfl_xor(W, d);
            const float mn = fmaxf(m, mo);
            const float da = m - mn, db = mo - mn;
            const float ea = __expf(da), eb = __expf(db);
            const float Wn = ea * (W + da * S) + eb * (Wo + db * So);
            S = ea * S + eb * So;
            W = Wn;
            m = mn;
        }

        // ---- per-row scalars
        const float H  = __logf(S) - W / S;          // entropy
        const float en = H * (1.0f / C_COLS);
        const float z  = 100.0f * (__logf(en) - __logf(1.0f - en)); // K=0.5, TEMP=0.01
        const float su = (z >= 0.f) ? 1.0f / (1.0f + __expf(-z))
                                    : __expf(z) / (1.0f + __expf(z));
        const float e2h = __expf(2.0f * H);
        const float th  = (e2h - 1.0f) / (e2h + 1.0f);  // tanh(H)
        const float omt = 2.0f / (e2h + 1.0f);          // 1 - tanh(H)

        const float cterm = (1.0f - su) * omt;
        const float uterm = su * th;

        if (s == 0) {
            if (xl == m) { s_ac += cterm; s_au += uterm; }
            else         { s_ic += cterm; s_iu += uterm; }
        }
    }

    // ---- wave reduction of the 4 partials
    #pragma unroll
    for (int off = 32; off > 0; off >>= 1) {
        s_ac += __shfl_xor(s_ac, off);
        s_au += __shfl_xor(s_au, off);
        s_ic += __shfl_xor(s_ic, off);
        s_iu += __shfl_xor(s_iu, off);
    }

    // ---- cross-wave reduction (4 waves/block), then ONE plain store per block
    __shared__ float red[4][4];
    if ((tid & 63) == 0) {
        red[wid][0] = s_ac; red[wid][1] = s_au;
        red[wid][2] = s_ic; red[wid][3] = s_iu;
    }
    __syncthreads();
    if (tid == 0) {
        partials[blockIdx.x] = make_float4(
            red[0][0] + red[1][0] + red[2][0] + red[3][0],
            red[0][1] + red[1][1] + red[2][1] + red[3][1],
            red[0][2] + red[1][2] + red[2][2] + red[3][2],
            red[0][3] + red[1][3] + red[2][3] + red[3][3]);
    }
}

__global__ __launch_bounds__(256) void avu_final(const float4* __restrict__ partials,
                                                 float* __restrict__ out) {
    const int tid = threadIdx.x;
    float4 a = make_float4(0.f, 0.f, 0.f, 0.f);
    #pragma unroll
    for (int k = 0; k < GRID_MAIN / 256; ++k) {
        const float4 v = partials[tid + 256 * k];
        a.x += v.x; a.y += v.y; a.z += v.z; a.w += v.w;
    }
    #pragma unroll
    for (int off = 32; off > 0; off >>= 1) {
        a.x += __shfl_xor(a.x, off);
        a.y += __shfl_xor(a.y, off);
        a.z += __shfl_xor(a.z, off);
        a.w += __shfl_xor(a.w, off);
    }
    __shared__ float4 red[4];
    if ((tid & 63) == 0) red[tid >> 6] = a;
    __syncthreads();
    if (tid == 0) {
        const float ac = red[0].x + red[1].x + red[2].x + red[3].x;
        const float au = red[0].y + red[1].y + red[2].y + red[3].y;
        const float ic = red[0].z + red[1].z + red[2].z + red[3].z;
        const float iu = red[0].w + red[1].w + red[2].w + red[3].w;
        const float avu = (ac + iu) / (ac + au + ic + iu + 1e-10f);
        out[0] = -logf(avu + 1e-10f);
    }
}

extern "C" void kernel_launch(void* const* d_in, const int* in_sizes, int n_in,
                              void* d_out, int out_size, void* d_ws, size_t ws_size,
                              hipStream_t stream) {
    const float* logits = (const float*)d_in[0];
    const int*   labels = (const int*)d_in[1];
    float*  out      = (float*)d_out;
    float4* partials = (float4*)d_ws;        // 1024 * 16 B = 16 KB

    const int nrows  = in_sizes[1];          // 524288
    const int ntiles = nrows / 64;           // 8192 (exact)

    avu_main<<<GRID_MAIN, 256, 0, stream>>>(logits, labels, partials, ntiles);
    avu_final<<<1, 256, 0, stream>>>(partials, out);
}